// Round 1
// baseline (1073.340 us; speedup 1.0000x reference)
//
#include <hip/hip_runtime.h>

// ---- types ----
typedef __bf16 bf16x8 __attribute__((ext_vector_type(8)));
typedef float  floatx4 __attribute__((ext_vector_type(4)));
typedef float  fvec4  __attribute__((ext_vector_type(4)));
typedef unsigned short ushort4v __attribute__((ext_vector_type(4)));

__device__ __forceinline__ unsigned short f2bf(float f) {
  unsigned int u = __float_as_uint(f);
  u = u + 0x7FFFu + ((u >> 16) & 1u);   // RNE
  return (unsigned short)(u >> 16);
}

// ---- prep: fp32 -> bf16 copies (w2, w3, x0). Layout [o][i][k] == MFMA-B row order (kappa = i*KW+k).
// groups of float4: w2: 950272, w3: 98304, x0: 131072  (total 1179648 = 4608 blocks * 256)
__global__ __launch_bounds__(256) void prep_kernel(
    const float* __restrict__ w2, const float* __restrict__ w3,
    const float* __restrict__ x, unsigned short* __restrict__ ws)
{
  int g = blockIdx.x * 256 + threadIdx.x;
  const float* src; unsigned short* dst;
  if (g < 950272)            { src = w2; dst = ws; }
  else if (g < 950272+98304) { g -= 950272; src = w3; dst = ws + 3801088; }
  else                       { g -= (950272+98304); src = x; dst = ws + 4194304; }
  fvec4 v = *reinterpret_cast<const fvec4*>(src + 4*g);
  ushort4v o;
  o[0] = f2bf(v[0]); o[1] = f2bf(v[1]); o[2] = f2bf(v[2]); o[3] = f2bf(v[3]);
  *reinterpret_cast<ushort4v*>(dst + 4*g) = o;
}

// ---- fill: zero the whole 256MB map, writing x on the diagonal.
// One float4 per thread; f -> (bd, r, c4): c4 = f&31, r = (f>>5)&127, bd = f>>12.
__global__ __launch_bounds__(256) void fill_kernel(
    float* __restrict__ out, const float* __restrict__ x)
{
  int f = blockIdx.x * 256 + threadIdx.x;       // 0 .. 16777215
  int c4 = f & 31, r = (f >> 5) & 127, bd = f >> 12;
  bool d = ((r >> 2) == c4);
  float xv = d ? x[bd * 128 + r] : 0.0f;
  int rl = r & 3;
  fvec4 v;
  v[0] = (d && rl == 0) ? xv : 0.0f;
  v[1] = (d && rl == 1) ? xv : 0.0f;
  v[2] = (d && rl == 2) ? xv : 0.0f;
  v[3] = (d && rl == 3) ? xv : 0.0f;
  *reinterpret_cast<fvec4*>(out + (long)4 * f) = v;
}

// ---- conv layer: Y[b,n,m] = sum_{i,k} W[n,i,k]*X[b,i,cs*m+k] + bias[n]
// WG: 256 thr = 4 waves. Tile M=32 (l-positions), N=64 (wave w owns n-sub 16w..16w+15), K = 256*KW.
// A staged in LDS (bf16, row pitch KS+8 to dodge bank conflicts); B-frags straight from global (L2-hot).
__global__ __launch_bounds__(256) void conv_kernel(
    const unsigned short* __restrict__ Xin,   // [16][256][Lin] bf16
    unsigned short* __restrict__ Xout,        // [16][256][Lout] bf16
    const unsigned short* __restrict__ WP,    // [256][KS] bf16
    const float* __restrict__ bias,           // [256]
    float* __restrict__ out,                  // [16][256][128][128] fp32
    int Lin, int Lout, int KW, int cs, int S, int off)
{
  const int KS = 256 * KW;
  const int pitch = KS + 8;
  extern __shared__ unsigned short LA[];      // [32][pitch]

  const int tid = threadIdx.x;
  const int b   = blockIdx.z;
  const int m0  = blockIdx.x * 32;
  const int n0  = blockIdx.y * 64;

  // stage A tile (zero-padded past Lout)
  {
    const int i = tid;                         // channel
    const unsigned short* xrow = Xin + (b * 256 + i) * Lin;
    for (int m = 0; m < 32; ++m) {
      int mm = m0 + m;
      int base = cs * mm;
      for (int k = 0; k < KW; ++k) {
        unsigned short v = 0;
        int p = base + k;
        if (mm < Lout && p < Lin) v = xrow[p];
        LA[m * pitch + i * KW + k] = v;
      }
    }
  }
  __syncthreads();

  const int wave = tid >> 6, lane = tid & 63;
  const int l15 = lane & 15, quad = lane >> 4;
  const int nn = n0 + wave * 16 + l15;         // B-frag row n == D-col n
  const unsigned short* wrow = WP + (long)nn * KS;
  const int kbase = quad * 8;

  floatx4 acc0 = {0.f, 0.f, 0.f, 0.f};
  floatx4 acc1 = {0.f, 0.f, 0.f, 0.f};

  const int niter = KS / 32;
  for (int kc = 0; kc < niter; ++kc) {
    int ko = kc * 32 + kbase;
    bf16x8 bfrag = *reinterpret_cast<const bf16x8*>(wrow + ko);
    bf16x8 a0 = *reinterpret_cast<const bf16x8*>(&LA[l15 * pitch + ko]);
    bf16x8 a1 = *reinterpret_cast<const bf16x8*>(&LA[(16 + l15) * pitch + ko]);
    acc0 = __builtin_amdgcn_mfma_f32_16x16x32_bf16(a0, bfrag, acc0, 0, 0, 0);
    acc1 = __builtin_amdgcn_mfma_f32_16x16x32_bf16(a1, bfrag, acc1, 0, 0, 0);
  }

  const float bv = bias[nn];
  unsigned short* xo = Xout + (b * 256 + nn) * Lout;
  const int obase = (b * 256 + nn) * 128;
#pragma unroll
  for (int r = 0; r < 4; ++r) {
    int m = m0 + quad * 4 + r;
    if (m < Lout) {
      float v = acc0[r] + bv;
      xo[m] = f2bf(v);
      out[(obase + S * m) * 128 + off + S * m] = v;
    }
    int m2 = m0 + 16 + quad * 4 + r;
    if (m2 < Lout) {
      float v = acc1[r] + bv;
      xo[m2] = f2bf(v);
      out[(obase + S * m2) * 128 + off + S * m2] = v;
    }
  }
}

extern "C" void kernel_launch(void* const* d_in, const int* in_sizes, int n_in,
                              void* d_out, int out_size, void* d_ws, size_t ws_size,
                              hipStream_t stream)
{
  const float* x  = (const float*)d_in[0];
  const float* w2 = (const float*)d_in[1];
  const float* b2 = (const float*)d_in[2];
  const float* w3 = (const float*)d_in[3];
  const float* b3 = (const float*)d_in[4];
  float* out = (float*)d_out;
  unsigned short* ws = (unsigned short*)d_ws;
  // ws layout (ushort elems): WP2 @0 (3801088), WP3 @3801088 (393216),
  // X0 @4194304 (16*256*128), then per-layer activation buffers. Total ~29 MB.

  prep_kernel<<<4608, 256, 0, stream>>>(w2, w3, x, ws);
  fill_kernel<<<65536, 256, 0, stream>>>(out, x);

  const int counts[3] = {15, 8, 8};
  int stride = 1, offset = 0, Lin = 128;
  int c2 = 0, c3 = 0;
  long xprev = 4194304;
  long xnext = 4194304 + (long)16 * 256 * 128;
  for (int ci = 0; ci < 3; ++ci) {
    for (int k = 0; k < counts[ci]; ++k) {
      offset += stride;
      int KW = (ci > 0 && k == 0) ? 3 : 2;
      int cs = (KW == 3) ? 2 : 1;
      int Lout = (Lin - KW) / cs + 1;
      const unsigned short* WPt; const float* bt;
      if (KW == 2) { WPt = ws + (long)c2 * 131072; bt = b2 + c2 * 256; ++c2; }
      else         { WPt = ws + 3801088 + (long)c3 * 196608; bt = b3 + c3 * 256; ++c3; }
      int pitch = 256 * KW + 8;
      size_t lds = (size_t)32 * pitch * sizeof(unsigned short);
      dim3 grid((Lout + 31) / 32, 4, 16);
      conv_kernel<<<grid, 256, lds, stream>>>(
          ws + xprev, ws + xnext, WPt, bt, out,
          Lin, Lout, KW, cs, stride, offset);
      xprev = xnext;
      xnext += (long)16 * 256 * Lout;
      Lin = Lout;
    }
    stride *= 2;
  }
}

// Round 2
// 717.114 us; speedup vs baseline: 1.4967x; 1.4967x over previous
//
#include <hip/hip_runtime.h>

// ---- types ----
typedef __bf16 bf16x8 __attribute__((ext_vector_type(8)));
typedef float  floatx4 __attribute__((ext_vector_type(4)));
typedef float  fvec4  __attribute__((ext_vector_type(4)));
typedef unsigned short ushort4v __attribute__((ext_vector_type(4)));
typedef unsigned short ushort8v __attribute__((ext_vector_type(8)));

__device__ __forceinline__ unsigned short f2bf(float f) {
  unsigned int u = __float_as_uint(f);
  u = u + 0x7FFFu + ((u >> 16) & 1u);   // RNE
  return (unsigned short)(u >> 16);
}

// ---- prep: fp32 -> bf16 copies (w2, w3, x0). Layout [o][i][k] == MFMA-B row order (kappa = i*KW+k).
// groups of float4: w2: 950272, w3: 98304, x0: 131072  (total 1179648 = 4608 blocks * 256)
__global__ __launch_bounds__(256) void prep_kernel(
    const float* __restrict__ w2, const float* __restrict__ w3,
    const float* __restrict__ x, unsigned short* __restrict__ ws)
{
  int g = blockIdx.x * 256 + threadIdx.x;
  const float* src; unsigned short* dst;
  if (g < 950272)            { src = w2; dst = ws; }
  else if (g < 950272+98304) { g -= 950272; src = w3; dst = ws + 3801088; }
  else                       { g -= (950272+98304); src = x; dst = ws + 4194304; }
  fvec4 v = *reinterpret_cast<const fvec4*>(src + 4*g);
  ushort4v o;
  o[0] = f2bf(v[0]); o[1] = f2bf(v[1]); o[2] = f2bf(v[2]); o[3] = f2bf(v[3]);
  *reinterpret_cast<ushort4v*>(dst + 4*g) = o;
}

// ---- fill: zero the whole 256MB map, writing x on the diagonal.
__global__ __launch_bounds__(256) void fill_kernel(
    float* __restrict__ out, const float* __restrict__ x)
{
  int f = blockIdx.x * 256 + threadIdx.x;       // 0 .. 16777215
  int c4 = f & 31, r = (f >> 5) & 127, bd = f >> 12;
  bool d = ((r >> 2) == c4);
  float xv = d ? x[bd * 128 + r] : 0.0f;
  int rl = r & 3;
  fvec4 v;
  v[0] = (d && rl == 0) ? xv : 0.0f;
  v[1] = (d && rl == 1) ? xv : 0.0f;
  v[2] = (d && rl == 2) ? xv : 0.0f;
  v[3] = (d && rl == 3) ? xv : 0.0f;
  *reinterpret_cast<fvec4*>(out + (long)4 * f) = v;
}

// ---- conv layer: Y[b,n,m] = sum_{i,k} W[n,i,k]*X[b,i,cs*m+k] + bias[n]
// WG: 256 thr = 4 waves. Tile M=32, N=64 (wave w owns n in [n0+16w, n0+16w+16)).
// Staging: thread t = channel t; vector-loads its row chunk (5 or 9 x ushort8),
// writes kappa-interleaved A tile to LDS (b32 writes for KW2 -> 2 lanes/bank, free).
// Activation buffers are row-pitched to a multiple of 8 elems (16B-aligned rows);
// tail over-reads land only in M-rows >= Lout which the epilogue discards.
template<int KW>
__global__ __launch_bounds__(256) void conv_kernel(
    const unsigned short* __restrict__ Xin,   // [16][256][Lpin] bf16 (pitched)
    unsigned short* __restrict__ Xout,        // [16][256][Lpout] bf16 (pitched)
    const unsigned short* __restrict__ WP,    // [256][KS] bf16
    const float* __restrict__ bias,           // [256]
    float* __restrict__ out,                  // [16][256][128][128] fp32
    int Lin, int Lpin, int Lout, int Lpout, int S, int off)
{
  constexpr int CS   = (KW == 3) ? 2 : 1;
  constexpr int KS   = 256 * KW;
  constexpr int pitch = KS + 8;               // elems; byte pitch mult of 16
  constexpr int NV   = (KW == 2) ? 5 : 9;     // ushort8 loads per thread
  __shared__ unsigned short LA[32 * pitch];

  const int tid = threadIdx.x;
  const int b   = blockIdx.z;
  const int m0  = blockIdx.x * 32;
  const int n0  = blockIdx.y * 64;

  // ---- stage A tile ----
  {
    const int i = tid;                         // channel
    const unsigned short* rp = Xin + ((b * 256 + i) * Lpin) + CS * m0;
    ushort8v xr[NV];
#pragma unroll
    for (int v = 0; v < NV; ++v)
      xr[v] = *reinterpret_cast<const ushort8v*>(rp + v * 8);
    const unsigned short* xs = reinterpret_cast<const unsigned short*>(xr);
    if (KW == 2) {
#pragma unroll
      for (int m = 0; m < 32; ++m) {
        unsigned int pk = (unsigned int)xs[m] | ((unsigned int)xs[m + 1] << 16);
        *reinterpret_cast<unsigned int*>(&LA[m * pitch + 2 * i]) = pk;
      }
    } else {
#pragma unroll
      for (int m = 0; m < 32; ++m) {
        int base = m * pitch + 3 * i;
        LA[base]     = xs[2 * m];
        LA[base + 1] = xs[2 * m + 1];
        LA[base + 2] = xs[2 * m + 2];
      }
    }
  }
  __syncthreads();

  const int wave = tid >> 6, lane = tid & 63;
  const int l15 = lane & 15, quad = lane >> 4;
  const int nn = n0 + wave * 16 + l15;
  const unsigned short* wrow = WP + (long)nn * KS;
  const int kbase = quad * 8;

  floatx4 acc0 = {0.f, 0.f, 0.f, 0.f};
  floatx4 acc1 = {0.f, 0.f, 0.f, 0.f};

  constexpr int niter = KS / 32;
#pragma unroll
  for (int kc = 0; kc < niter; ++kc) {
    int ko = kc * 32 + kbase;
    bf16x8 bfrag = *reinterpret_cast<const bf16x8*>(wrow + ko);
    bf16x8 a0 = *reinterpret_cast<const bf16x8*>(&LA[l15 * pitch + ko]);
    bf16x8 a1 = *reinterpret_cast<const bf16x8*>(&LA[(16 + l15) * pitch + ko]);
    acc0 = __builtin_amdgcn_mfma_f32_16x16x32_bf16(a0, bfrag, acc0, 0, 0, 0);
    acc1 = __builtin_amdgcn_mfma_f32_16x16x32_bf16(a1, bfrag, acc1, 0, 0, 0);
  }

  const float bv = bias[nn];
  unsigned short* xo = Xout + (b * 256 + nn) * Lpout;
  const int obase = (b * 256 + nn) * 128;
#pragma unroll
  for (int r = 0; r < 4; ++r) {
    int m = m0 + quad * 4 + r;
    if (m < Lout) {
      float v = acc0[r] + bv;
      xo[m] = f2bf(v);
      out[(obase + S * m) * 128 + off + S * m] = v;
    }
    int m2 = m0 + 16 + quad * 4 + r;
    if (m2 < Lout) {
      float v = acc1[r] + bv;
      xo[m2] = f2bf(v);
      out[(obase + S * m2) * 128 + off + S * m2] = v;
    }
  }
}

extern "C" void kernel_launch(void* const* d_in, const int* in_sizes, int n_in,
                              void* d_out, int out_size, void* d_ws, size_t ws_size,
                              hipStream_t stream)
{
  const float* x  = (const float*)d_in[0];
  const float* w2 = (const float*)d_in[1];
  const float* b2 = (const float*)d_in[2];
  const float* w3 = (const float*)d_in[3];
  const float* b3 = (const float*)d_in[4];
  float* out = (float*)d_out;
  unsigned short* ws = (unsigned short*)d_ws;
  // ws layout (ushort elems): WP2 @0 (3801088), WP3 @3801088 (393216),
  // X0 @4194304 (16*256*128), then per-layer pitched activation buffers (+64 slack each).

  prep_kernel<<<4608, 256, 0, stream>>>(w2, w3, x, ws);
  fill_kernel<<<65536, 256, 0, stream>>>(out, x);

  const int counts[3] = {15, 8, 8};
  int stride = 1, offset = 0;
  int Lin = 128, Lpin = 128;
  int c2 = 0, c3 = 0;
  long xprev = 4194304;
  long xnext = xprev + (long)16 * 256 * 128 + 64;
  for (int ci = 0; ci < 3; ++ci) {
    for (int k = 0; k < counts[ci]; ++k) {
      offset += stride;
      int KW = (ci > 0 && k == 0) ? 3 : 2;
      int cs = (KW == 3) ? 2 : 1;
      int Lout = (Lin - KW) / cs + 1;
      int Lpout = (Lout + 7) & ~7;
      const unsigned short* WPt; const float* bt;
      if (KW == 2) { WPt = ws + (long)c2 * 131072; bt = b2 + c2 * 256; ++c2; }
      else         { WPt = ws + 3801088 + (long)c3 * 196608; bt = b3 + c3 * 256; ++c3; }
      dim3 grid((Lout + 31) / 32, 4, 16);
      if (KW == 2)
        conv_kernel<2><<<grid, 256, 0, stream>>>(
            ws + xprev, ws + xnext, WPt, bt, out, Lin, Lpin, Lout, Lpout, stride, offset);
      else
        conv_kernel<3><<<grid, 256, 0, stream>>>(
            ws + xprev, ws + xnext, WPt, bt, out, Lin, Lpin, Lout, Lpout, stride, offset);
      xprev = xnext;
      xnext += (long)16 * 256 * Lpout + 64;
      Lin = Lout; Lpin = Lpout;
    }
    stride *= 2;
  }
}

// Round 3
// 582.682 us; speedup vs baseline: 1.8421x; 1.2307x over previous
//
#include <hip/hip_runtime.h>

// ---- types ----
typedef __bf16 bf16x8 __attribute__((ext_vector_type(8)));
typedef float  floatx4 __attribute__((ext_vector_type(4)));
typedef float  fvec4  __attribute__((ext_vector_type(4)));
typedef unsigned short ushort4v __attribute__((ext_vector_type(4)));
typedef unsigned short ushort8v __attribute__((ext_vector_type(8)));

__device__ __forceinline__ unsigned short f2bf(float f) {
  unsigned int u = __float_as_uint(f);
  u = u + 0x7FFFu + ((u >> 16) & 1u);   // RNE
  return (unsigned short)(u >> 16);
}

// ws layout (byte offsets):
//   0        : WP2 bf16  (29 * 256 * 512)   = 7,602,176 B
//   7602176  : WP3 bf16  (2 * 256 * 768)    =   786,432 B
//   8388608  : X0 bf16   (16*256*128)       = 1,048,576 B, then pitched per-layer bf16 activ.
//   64 MiB   : Y fp32    [31][16*256][128]  = 65 MB compact stripe values
#define WP3_OFF   3801088    // ushort elems
#define X0_OFF    4194304    // ushort elems
#define Y_OFF_B   (64u << 20)

// ---- prep: fp32 -> bf16 copies (w2, w3, x0). Layout [o][i][k] == MFMA-B row order.
__global__ __launch_bounds__(256) void prep_kernel(
    const float* __restrict__ w2, const float* __restrict__ w3,
    const float* __restrict__ x, unsigned short* __restrict__ ws)
{
  int g = blockIdx.x * 256 + threadIdx.x;
  const float* src; unsigned short* dst;
  if (g < 950272)            { src = w2; dst = ws; }
  else if (g < 950272+98304) { g -= 950272; src = w3; dst = ws + WP3_OFF; }
  else                       { g -= (950272+98304); src = x; dst = ws + X0_OFF; }
  fvec4 v = *reinterpret_cast<const fvec4*>(src + 4*g);
  ushort4v o;
  o[0] = f2bf(v[0]); o[1] = f2bf(v[1]); o[2] = f2bf(v[2]); o[3] = f2bf(v[3]);
  *reinterpret_cast<ushort4v*>(dst + 4*g) = o;
}

// ---- conv layer: Y[b,n,m] = sum_{i,k} W[n,i,k]*X[b,i,cs*m+k] + bias[n]
// Writes compact bf16 (chain input) + compact fp32 (for assemble). No d_out traffic.
template<int KW>
__global__ __launch_bounds__(256) void conv_kernel(
    const unsigned short* __restrict__ Xin,   // [16*256][Lpin] bf16
    unsigned short* __restrict__ Xout,        // [16*256][Lpout] bf16
    const unsigned short* __restrict__ WP,    // [256][KS] bf16
    const float* __restrict__ bias,           // [256]
    float* __restrict__ Yl,                   // [16*256][128] fp32 compact (this layer)
    int Lin, int Lpin, int Lout, int Lpout)
{
  constexpr int CS   = (KW == 3) ? 2 : 1;
  constexpr int KS   = 256 * KW;
  constexpr int pitch = KS + 8;
  constexpr int NV   = (KW == 2) ? 5 : 9;
  __shared__ unsigned short LA[32 * pitch];

  const int tid = threadIdx.x;
  const int b   = blockIdx.z;
  const int m0  = blockIdx.x * 32;
  const int n0  = blockIdx.y * 64;

  // ---- stage A tile (vectorized row loads; tail garbage only feeds m>=Lout) ----
  {
    const int i = tid;
    const unsigned short* rp = Xin + ((b * 256 + i) * Lpin) + CS * m0;
    ushort8v xr[NV];
#pragma unroll
    for (int v = 0; v < NV; ++v)
      xr[v] = *reinterpret_cast<const ushort8v*>(rp + v * 8);
    const unsigned short* xs = reinterpret_cast<const unsigned short*>(xr);
    if (KW == 2) {
#pragma unroll
      for (int m = 0; m < 32; ++m) {
        unsigned int pk = (unsigned int)xs[m] | ((unsigned int)xs[m + 1] << 16);
        *reinterpret_cast<unsigned int*>(&LA[m * pitch + 2 * i]) = pk;
      }
    } else {
#pragma unroll
      for (int m = 0; m < 32; ++m) {
        int base = m * pitch + 3 * i;
        LA[base]     = xs[2 * m];
        LA[base + 1] = xs[2 * m + 1];
        LA[base + 2] = xs[2 * m + 2];
      }
    }
  }
  __syncthreads();

  const int wave = tid >> 6, lane = tid & 63;
  const int l15 = lane & 15, quad = lane >> 4;
  const int nn = n0 + wave * 16 + l15;
  const unsigned short* wrow = WP + (long)nn * KS;
  const int kbase = quad * 8;

  floatx4 acc0 = {0.f, 0.f, 0.f, 0.f};
  floatx4 acc1 = {0.f, 0.f, 0.f, 0.f};

  constexpr int niter = KS / 32;
#pragma unroll
  for (int kc = 0; kc < niter; ++kc) {
    int ko = kc * 32 + kbase;
    bf16x8 bfrag = *reinterpret_cast<const bf16x8*>(wrow + ko);
    bf16x8 a0 = *reinterpret_cast<const bf16x8*>(&LA[l15 * pitch + ko]);
    bf16x8 a1 = *reinterpret_cast<const bf16x8*>(&LA[(16 + l15) * pitch + ko]);
    acc0 = __builtin_amdgcn_mfma_f32_16x16x32_bf16(a0, bfrag, acc0, 0, 0, 0);
    acc1 = __builtin_amdgcn_mfma_f32_16x16x32_bf16(a1, bfrag, acc1, 0, 0, 0);
  }

  const float bv = bias[nn];
  const int row = b * 256 + nn;
  unsigned short* xo = Xout + row * Lpout;
  float* yo = Yl + row * 128;
#pragma unroll
  for (int r = 0; r < 4; ++r) {
    int m = m0 + quad * 4 + r;
    if (m < Lout) {
      float v = acc0[r] + bv;
      xo[m] = f2bf(v);
      yo[m] = v;
    }
    int m2 = m0 + 16 + quad * 4 + r;
    if (m2 < Lout) {
      float v = acc1[r] + bv;
      xo[m2] = f2bf(v);
      yo[m2] = v;
    }
  }
}

// ---- assemble: write the whole 256MB map coalesced, composing zeros/diag/stripes.
// Validity of a stripe point at (r, c) depends only on d=c-r and r's divisibility:
//   d==0 -> diag (x);  1<=d<=15 -> layer d-1 (st=1, m=r);
//   17<=d<=31, d odd, r%2==0 -> layer 15+(d-17)/2 (st=2, m=r/2);
//   35<=d<=63, d%4==3, r%4==0 -> layer 23+(d-35)/4 (st=4, m=r/4).
// (m < Lout is automatic from c < 128 — proved offline.)
__global__ __launch_bounds__(256) void assemble_kernel(
    float* __restrict__ out, const float* __restrict__ x, const float* __restrict__ Y)
{
  const int f0 = blockIdx.x * 256 + threadIdx.x;   // 0 .. 524287
  const int c4 = f0 & 31, r = (f0 >> 5) & 127;
  const int bch0 = f0 >> 12;                        // advances +128 per iter

  int addr[4];    // Y elem offset (minus bch*128 term), or -1
  bool dg[4];
#pragma unroll
  for (int jj = 0; jj < 4; ++jj) {
    int c = 4 * c4 + jj;
    int d = c - r;
    dg[jj] = (d == 0);
    int a = -1;
    if (d >= 1 && d <= 15) {
      a = (d - 1) * 524288 + r;
    } else if (d >= 17 && d <= 31 && (d & 1) == 1 && (r & 1) == 0) {
      a = (15 + ((d - 17) >> 1)) * 524288 + (r >> 1);
    } else if (d >= 35 && d <= 63 && (d & 3) == 3 && (r & 3) == 0) {
      a = (23 + ((d - 35) >> 2)) * 524288 + (r >> 2);
    }
    addr[jj] = a;
  }

  for (int it = 0; it < 32; ++it) {
    int bch = bch0 + it * 128;
    fvec4 v = {0.f, 0.f, 0.f, 0.f};
    int boff = bch * 128;
#pragma unroll
    for (int jj = 0; jj < 4; ++jj) {
      if (dg[jj])            v[jj] = x[boff + r];
      else if (addr[jj] >= 0) v[jj] = Y[addr[jj] + boff];
    }
    *reinterpret_cast<fvec4*>(out + (long)4 * (f0 + it * 524288)) = v;
  }
}

extern "C" void kernel_launch(void* const* d_in, const int* in_sizes, int n_in,
                              void* d_out, int out_size, void* d_ws, size_t ws_size,
                              hipStream_t stream)
{
  const float* x  = (const float*)d_in[0];
  const float* w2 = (const float*)d_in[1];
  const float* b2 = (const float*)d_in[2];
  const float* w3 = (const float*)d_in[3];
  const float* b3 = (const float*)d_in[4];
  float* out = (float*)d_out;
  unsigned short* ws = (unsigned short*)d_ws;
  float* Y = (float*)((char*)d_ws + Y_OFF_B);

  prep_kernel<<<4608, 256, 0, stream>>>(w2, w3, x, ws);

  const int counts[3] = {15, 8, 8};
  int stride = 1, offset = 0;
  int Lin = 128, Lpin = 128;
  int c2 = 0, c3 = 0, lidx = 0;
  long xprev = X0_OFF;
  long xnext = xprev + (long)16 * 256 * 128 + 64;
  for (int ci = 0; ci < 3; ++ci) {
    for (int k = 0; k < counts[ci]; ++k) {
      offset += stride;
      int KW = (ci > 0 && k == 0) ? 3 : 2;
      int cs = (KW == 3) ? 2 : 1;
      int Lout = (Lin - KW) / cs + 1;
      int Lpout = (Lout + 7) & ~7;
      const unsigned short* WPt; const float* bt;
      if (KW == 2) { WPt = ws + (long)c2 * 131072; bt = b2 + c2 * 256; ++c2; }
      else         { WPt = ws + WP3_OFF + (long)c3 * 196608; bt = b3 + c3 * 256; ++c3; }
      dim3 grid((Lout + 31) / 32, 4, 16);
      if (KW == 2)
        conv_kernel<2><<<grid, 256, 0, stream>>>(
            ws + xprev, ws + xnext, WPt, bt, Y + (long)lidx * 524288,
            Lin, Lpin, Lout, Lpout);
      else
        conv_kernel<3><<<grid, 256, 0, stream>>>(
            ws + xprev, ws + xnext, WPt, bt, Y + (long)lidx * 524288,
            Lin, Lpin, Lout, Lpout);
      ++lidx;
      xprev = xnext;
      xnext += (long)16 * 256 * Lpout + 64;
      Lin = Lout; Lpin = Lpout;
    }
    stride *= 2;
  }

  assemble_kernel<<<2048, 256, 0, stream>>>(out, x, Y);
}